// Round 4
// baseline (106.991 us; speedup 1.0000x reference)
//
#include <hip/hip_runtime.h>

#define NDIM 1024
#define CH 16
#define ROW_FLOATS (NDIM * CH)      // 16384 floats per row of W
#define ROW_F4 (ROW_FLOATS / 4)     // 4096 float4 per row

__device__ inline float4 f4add(float4 a, float4 b) {
    return make_float4(a.x + b.x, a.y + b.y, a.z + b.z, a.w + b.w);
}
__device__ inline float4 f4shfl_xor(float4 v, int m) {
    return make_float4(__shfl_xor(v.x, m), __shfl_xor(v.y, m),
                       __shfl_xor(v.z, m), __shfl_xor(v.w, m));
}

// ===========================================================================
// FUSED PATH (requires ~4.7 MB workspace)
// ===========================================================================
// kF1: single pass over W producing BOTH chunked row partials and col partials.
// Block = 64 cols x 64 rows tile. Thread t -> (j_local = t>>2, cq = t&3).
// Column sums: pure register accumulation over the 64 rows.
// Row sums: 4x shfl_xor (masks 4,8,16,32 = j_local lane bits) -> per-wave LDS
// slice -> cross-wave reduce in epilogue. Deterministic, no atomics.
// rowpart[z][chunk=bj][i][c], colpart[z][chunk=bi][j][c]  (16 chunks each)
// ---------------------------------------------------------------------------
__global__ __launch_bounds__(256) void k_fused(const float* __restrict__ W1,
                                               const float* __restrict__ W2,
                                               float* __restrict__ rowpart,
                                               float* __restrict__ colpart) {
    int t  = threadIdx.x;
    int bj = blockIdx.x, bi = blockIdx.y, z = blockIdx.z;
    int j0 = bj * 64, i0 = bi * 64;
    const float4* base = (const float4*)(z ? W2 : W1)
                       + (size_t)i0 * ROW_F4 + j0 * 4 + t;   // 4 float4 per j
    __shared__ float rowacc[4][64][16];   // [wave][row][ch] — 16 KB
    int w = t >> 6, lane = t & 63;
    float4 colacc = make_float4(0.f, 0.f, 0.f, 0.f);
#pragma unroll 4
    for (int k = 0; k < 64; ++k) {
        float4 v = base[(size_t)k * ROW_F4];
        colacc = f4add(colacc, v);
        float4 vr = v;
        vr = f4add(vr, f4shfl_xor(vr, 4));
        vr = f4add(vr, f4shfl_xor(vr, 8));
        vr = f4add(vr, f4shfl_xor(vr, 16));
        vr = f4add(vr, f4shfl_xor(vr, 32));
        if (lane < 4) {   // lane == cq; holds sum over this wave's 16 j_locals
            rowacc[w][k][lane * 4 + 0] = vr.x;
            rowacc[w][k][lane * 4 + 1] = vr.y;
            rowacc[w][k][lane * 4 + 2] = vr.z;
            rowacc[w][k][lane * 4 + 3] = vr.w;
        }
    }
    int jl = t >> 2, cq = t & 3;
    {   // column partial: this thread owns (j0+jl, channels 4cq..4cq+3)
        size_t coff = (((size_t)z * 16 + bi) * NDIM + (j0 + jl)) * CH + cq * 4;
        *(float4*)(colpart + coff) = colacc;
    }
    __syncthreads();
    {   // row partial: thread -> (row r = t>>2, cq), reduce the 4 wave slices
        int r = t >> 2;
        const float4* ra = (const float4*)&rowacc[0][0][0];  // [(w*64+r)*4 + cq]
        float4 s = f4add(f4add(ra[(0 * 64 + r) * 4 + cq], ra[(1 * 64 + r) * 4 + cq]),
                         f4add(ra[(2 * 64 + r) * 4 + cq], ra[(3 * 64 + r) * 4 + cq]));
        size_t roff = (((size_t)z * 16 + bj) * NDIM + (i0 + r)) * CH + cq * 4;
        *(float4*)(rowpart + roff) = s;
    }
}

// kF2: reduce the 16 chunks -> final rowsum[z][i][c], colsum[z][j][c]
__global__ __launch_bounds__(256) void k_finalize(const float* __restrict__ rowpart,
                                                  const float* __restrict__ colpart,
                                                  float* __restrict__ rowsumF,
                                                  float* __restrict__ colsumF) {
    int gt  = blockIdx.x * 256 + threadIdx.x;  // 0..65535
    int sel = gt >> 15;
    int rem = gt & 32767;                      // z*16384 + idx
    const float* src = sel ? colpart : rowpart;
    float* dst       = sel ? colsumF : rowsumF;
    int z = rem >> 14, idx = rem & 16383;
    const float* p = src + (size_t)z * 16 * 16384 + idx;
    float s = 0.f;
#pragma unroll
    for (int ch = 0; ch < 16; ++ch) s += p[ch * 16384];
    dst[rem] = s;
}

// ===========================================================================
// Shared / fallback kernels
// ===========================================================================
__global__ __launch_bounds__(256) void k_rowsum(const float* __restrict__ W1,
                                                const float* __restrict__ W2,
                                                float* __restrict__ rowsum) {
    int i = blockIdx.x;
    int z = blockIdx.y;
    const float4* W = (const float4*)((z ? W2 : W1) + (size_t)i * ROW_FLOATS);
    int t = threadIdx.x;
    float4 a = make_float4(0.f, 0.f, 0.f, 0.f);
#pragma unroll 4
    for (int k = 0; k < ROW_F4 / 256; ++k) {
        float4 v = W[t + 256 * k];
        a = f4add(a, v);
    }
    __shared__ float4 lds[256];
    lds[t] = a;
    __syncthreads();
    if (t < 64) {
        float4 s = lds[t];
#pragma unroll
        for (int o = 1; o < 4; ++o) s = f4add(s, lds[t + 64 * o]);
        lds[t] = s;
    }
    __syncthreads();
    if (t < 4) {
        float4 s = make_float4(0.f, 0.f, 0.f, 0.f);
#pragma unroll
        for (int m = 0; m < 16; ++m) s = f4add(s, lds[t + 4 * m]);
        float* dst = rowsum + ((size_t)z * NDIM + i) * CH + 4 * t;
        dst[0] = s.x; dst[1] = s.y; dst[2] = s.z; dst[3] = s.w;
    }
}

__global__ __launch_bounds__(256) void k_colsum_partial(const float* __restrict__ W1,
                                                        const float* __restrict__ W2,
                                                        float* __restrict__ partial) {
    int t   = threadIdx.x;
    int f4  = t & 31;
    int oct = t >> 5;
    int j0  = blockIdx.x * 8;
    int i0  = blockIdx.y * 512;
    int z   = blockIdx.z;
    const float4* base =
        (const float4*)((z ? W2 : W1) + (size_t)i0 * ROW_FLOATS + (size_t)j0 * CH);
    float4 a = make_float4(0.f, 0.f, 0.f, 0.f);
#pragma unroll 4
    for (int k = 0; k < 64; ++k) {
        int i = 8 * k + oct;
        a = f4add(a, base[(size_t)i * ROW_F4 + f4]);
    }
    __shared__ float4 lds[256];
    lds[t] = a;
    __syncthreads();
    if (t < 32) {
        float4 s = lds[t];
#pragma unroll
        for (int o = 1; o < 8; ++o) s = f4add(s, lds[t + 32 * o]);
        int j  = j0 + (t >> 2);
        int c0 = (t & 3) * 4;
        float* dst = partial + (((size_t)z * 2 + blockIdx.y) * NDIM + j) * CH + c0;
        dst[0] = s.x; dst[1] = s.y; dst[2] = s.z; dst[3] = s.w;
    }
}

__global__ __launch_bounds__(256) void k_sums(const float* __restrict__ rowsum,
                                              const float* __restrict__ b1,
                                              const float* __restrict__ b2,
                                              float* __restrict__ sums) {
    int tgt = blockIdx.x;
    const float* src = (tgt == 0) ? rowsum
                     : (tgt == 1) ? rowsum + 16384
                     : (tgt == 2) ? b1 : b2;
    int t = threadIdx.x;
    const float4* s4 = (const float4*)src;
    float4 a = make_float4(0.f, 0.f, 0.f, 0.f);
#pragma unroll
    for (int k = 0; k < 16; ++k) a = f4add(a, s4[t + 256 * k]);
    __shared__ float4 lds[256];
    lds[t] = a;
    __syncthreads();
    if (t < 64) {
        float4 s = lds[t];
#pragma unroll
        for (int o = 1; o < 4; ++o) s = f4add(s, lds[t + 64 * o]);
        lds[t] = s;
    }
    __syncthreads();
    if (t < 4) {
        float4 s = make_float4(0.f, 0.f, 0.f, 0.f);
#pragma unroll
        for (int m = 0; m < 16; ++m) s = f4add(s, lds[t + 4 * m]);
        float* dst = sums + tgt * 16 + 4 * t;
        dst[0] = s.x; dst[1] = s.y; dst[2] = s.z; dst[3] = s.w;
    }
}

// k_smalls2: fused-path variant (reads final rowsumF/colsumF directly)
__global__ __launch_bounds__(256) void k_smalls2(const float* __restrict__ rowsum,
                                                 const float* __restrict__ colsum,
                                                 const float* __restrict__ sums,
                                                 const float* __restrict__ b1,
                                                 const float* __restrict__ b2,
                                                 const float* __restrict__ th0,
                                                 const float* __restrict__ th1,
                                                 const float* __restrict__ th2,
                                                 const float* __restrict__ th3,
                                                 const float* __restrict__ bias0,
                                                 const float* __restrict__ bias1,
                                                 const float* __restrict__ bias2,
                                                 const float* __restrict__ bias3,
                                                 float* __restrict__ R0, float* __restrict__ C0,
                                                 float* __restrict__ R1, float* __restrict__ C1,
                                                 float* __restrict__ out2, float* __restrict__ out3) {
    int gt = blockIdx.x * 256 + threadIdx.x;
    int i = gt >> 4, o = gt & 15;
    const float* rs1 = rowsum + i * 16;
    const float* rs2 = rowsum + 16384 + i * 16;
    const float* cs1 = colsum + i * 16;
    const float* cs2 = colsum + 16384 + i * 16;
    const float* b1i = b1 + i * 16;
    const float* b2i = b2 + i * 16;
    float r0 = 0.f, c0a = 0.f, r1 = 0.f, c1a = 0.f, o2 = 0.f, o3 = 0.f;
    float k0 = 0.f, k1 = 0.f, k2 = 0.f, k3 = 0.f;
#pragma unroll
    for (int c = 0; c < 16; ++c) {
        float sW1 = sums[c], sW2 = sums[16 + c], sb1 = sums[32 + c], sb2 = sums[48 + c];
        r0  += rs1[c] * th0[(1 * 16 + c) * 16 + o];
        c0a += cs1[c] * th0[(2 * 16 + c) * 16 + o]
             + rs2[c] * th0[(4 * 16 + c) * 16 + o]
             + b1i[c] * th0[(6 * 16 + c) * 16 + o];
        k0  += sW1 * th0[(3 * 16 + c) * 16 + o] + sW2 * th0[(5 * 16 + c) * 16 + o]
             + sb1 * th0[(7 * 16 + c) * 16 + o] + sb2 * th0[(8 * 16 + c) * 16 + o];
        r1  += cs1[c] * th1[(0 * 16 + c) * 16 + o]
             + rs2[c] * th1[(3 * 16 + c) * 16 + o]
             + b1i[c] * th1[(6 * 16 + c) * 16 + o];
        c1a += cs2[c] * th1[(4 * 16 + c) * 16 + o]
             + b2i[c] * th1[(8 * 16 + c) * 16 + o];
        k1  += sW1 * th1[(1 * 16 + c) * 16 + o] + sW2 * th1[(5 * 16 + c) * 16 + o]
             + sb1 * th1[(7 * 16 + c) * 16 + o] + sb2 * th1[(9 * 16 + c) * 16 + o];
        o2  += cs1[c] * th2[(0 * 16 + c) * 16 + o]
             + rs2[c] * th2[(2 * 16 + c) * 16 + o]
             + b1i[c] * th2[(4 * 16 + c) * 16 + o];
        k2  += sW1 * th2[(1 * 16 + c) * 16 + o] + sW2 * th2[(3 * 16 + c) * 16 + o]
             + sb1 * th2[(5 * 16 + c) * 16 + o] + sb2 * th2[(6 * 16 + c) * 16 + o];
        o3  += cs2[c] * th3[(1 * 16 + c) * 16 + o]
             + b2i[c] * th3[(4 * 16 + c) * 16 + o];
        k3  += sW1 * th3[(0 * 16 + c) * 16 + o] + sW2 * th3[(2 * 16 + c) * 16 + o]
             + sb1 * th3[(3 * 16 + c) * 16 + o] + sb2 * th3[(5 * 16 + c) * 16 + o];
    }
    R0[gt]   = r0;
    C0[gt]   = c0a + k0 + bias0[o];
    R1[gt]   = r1;
    C1[gt]   = c1a + k1 + bias1[o];
    out2[gt] = o2 + k2 + bias2[o];
    out3[gt] = o3 + k3 + bias3[o];
}

// fallback variant (2-chunk colsum partials)
__global__ __launch_bounds__(256) void k_smalls(const float* __restrict__ rowsum,
                                                const float* __restrict__ partial,
                                                const float* __restrict__ sums,
                                                const float* __restrict__ b1,
                                                const float* __restrict__ b2,
                                                const float* __restrict__ th0,
                                                const float* __restrict__ th1,
                                                const float* __restrict__ th2,
                                                const float* __restrict__ th3,
                                                const float* __restrict__ bias0,
                                                const float* __restrict__ bias1,
                                                const float* __restrict__ bias2,
                                                const float* __restrict__ bias3,
                                                float* __restrict__ R0, float* __restrict__ C0,
                                                float* __restrict__ R1, float* __restrict__ C1,
                                                float* __restrict__ out2, float* __restrict__ out3) {
    int gt = blockIdx.x * 256 + threadIdx.x;
    int i = gt >> 4, o = gt & 15;
    const float* rs1 = rowsum + i * 16;
    const float* rs2 = rowsum + 16384 + i * 16;
    const float* b1i = b1 + i * 16;
    const float* b2i = b2 + i * 16;
    float cs1[16], cs2[16];
#pragma unroll
    for (int c = 0; c < 16; ++c) {
        cs1[c] = partial[i * 16 + c]         + partial[16384 + i * 16 + c];
        cs2[c] = partial[32768 + i * 16 + c] + partial[49152 + i * 16 + c];
    }
    float r0 = 0.f, c0a = 0.f, r1 = 0.f, c1a = 0.f, o2 = 0.f, o3 = 0.f;
    float k0 = 0.f, k1 = 0.f, k2 = 0.f, k3 = 0.f;
#pragma unroll
    for (int c = 0; c < 16; ++c) {
        float sW1 = sums[c], sW2 = sums[16 + c], sb1 = sums[32 + c], sb2 = sums[48 + c];
        r0  += rs1[c] * th0[(1 * 16 + c) * 16 + o];
        c0a += cs1[c] * th0[(2 * 16 + c) * 16 + o]
             + rs2[c] * th0[(4 * 16 + c) * 16 + o]
             + b1i[c] * th0[(6 * 16 + c) * 16 + o];
        k0  += sW1 * th0[(3 * 16 + c) * 16 + o] + sW2 * th0[(5 * 16 + c) * 16 + o]
             + sb1 * th0[(7 * 16 + c) * 16 + o] + sb2 * th0[(8 * 16 + c) * 16 + o];
        r1  += cs1[c] * th1[(0 * 16 + c) * 16 + o]
             + rs2[c] * th1[(3 * 16 + c) * 16 + o]
             + b1i[c] * th1[(6 * 16 + c) * 16 + o];
        c1a += cs2[c] * th1[(4 * 16 + c) * 16 + o]
             + b2i[c] * th1[(8 * 16 + c) * 16 + o];
        k1  += sW1 * th1[(1 * 16 + c) * 16 + o] + sW2 * th1[(5 * 16 + c) * 16 + o]
             + sb1 * th1[(7 * 16 + c) * 16 + o] + sb2 * th1[(9 * 16 + c) * 16 + o];
        o2  += cs1[c] * th2[(0 * 16 + c) * 16 + o]
             + rs2[c] * th2[(2 * 16 + c) * 16 + o]
             + b1i[c] * th2[(4 * 16 + c) * 16 + o];
        k2  += sW1 * th2[(1 * 16 + c) * 16 + o] + sW2 * th2[(3 * 16 + c) * 16 + o]
             + sb1 * th2[(5 * 16 + c) * 16 + o] + sb2 * th2[(6 * 16 + c) * 16 + o];
        o3  += cs2[c] * th3[(1 * 16 + c) * 16 + o]
             + b2i[c] * th3[(4 * 16 + c) * 16 + o];
        k3  += sW1 * th3[(0 * 16 + c) * 16 + o] + sW2 * th3[(2 * 16 + c) * 16 + o]
             + sb1 * th3[(3 * 16 + c) * 16 + o] + sb2 * th3[(5 * 16 + c) * 16 + o];
    }
    R0[gt]   = r0;
    C0[gt]   = c0a + k0 + bias0[o];
    R1[gt]   = r1;
    C1[gt]   = c1a + k1 + bias1[o];
    out2[gt] = o2 + k2 + bias2[o];
    out3[gt] = o3 + k3 + bias3[o];
}

// ---------------------------------------------------------------------------
// k_main: streaming pass.
//   out0[i,j,:] = W1[i,j,:]·θ0_0 + R0[i] + C0[j]
//   out1[i,j,:] = W2[i,j,:]·θ1_2 + R1[i] + C1[j]
// ---------------------------------------------------------------------------
__global__ __launch_bounds__(256) void k_main(const float* __restrict__ W1,
                                              const float* __restrict__ W2,
                                              const float* __restrict__ R0,
                                              const float* __restrict__ C0,
                                              const float* __restrict__ R1,
                                              const float* __restrict__ C1,
                                              const float* __restrict__ th0,
                                              const float* __restrict__ th1,
                                              float* __restrict__ out0,
                                              float* __restrict__ out1) {
    int z = blockIdx.z;
    const float* W  = z ? W2 : W1;
    const float* R  = z ? R1 : R0;
    const float* Cc = z ? C1 : C0;
    const float* TH = z ? th1 : th0;
    float* out      = z ? out1 : out0;

    int t = threadIdx.x;
    int i = blockIdx.y;
    int j = blockIdx.x * 256 + t;

    __shared__ float th[256];
    __shared__ float r[16];
    th[t] = TH[t];
    if (t < 16) r[t] = R[i * 16 + t];
    __syncthreads();

    size_t base = ((size_t)i * NDIM + j) * CH;
    const float4* xp = (const float4*)(W + base);
    float4 x0 = xp[0], x1 = xp[1], x2 = xp[2], x3 = xp[3];
    float x[16] = {x0.x, x0.y, x0.z, x0.w, x1.x, x1.y, x1.z, x1.w,
                   x2.x, x2.y, x2.z, x2.w, x3.x, x3.y, x3.z, x3.w};

    const float4* cj = (const float4*)(Cc + j * 16);
    float4 c0 = cj[0], c1 = cj[1], c2 = cj[2], c3 = cj[3];
    float acc[16] = {c0.x, c0.y, c0.z, c0.w, c1.x, c1.y, c1.z, c1.w,
                     c2.x, c2.y, c2.z, c2.w, c3.x, c3.y, c3.z, c3.w};
#pragma unroll
    for (int o = 0; o < 16; ++o) acc[o] += r[o];
#pragma unroll
    for (int c = 0; c < 16; ++c) {
        float xv = x[c];
#pragma unroll
        for (int o = 0; o < 16; ++o) acc[o] += xv * th[c * 16 + o];
    }
    float4* op = (float4*)(out + base);
    op[0] = make_float4(acc[0],  acc[1],  acc[2],  acc[3]);
    op[1] = make_float4(acc[4],  acc[5],  acc[6],  acc[7]);
    op[2] = make_float4(acc[8],  acc[9],  acc[10], acc[11]);
    op[3] = make_float4(acc[12], acc[13], acc[14], acc[15]);
}

extern "C" void kernel_launch(void* const* d_in, const int* in_sizes, int n_in,
                              void* d_out, int out_size, void* d_ws, size_t ws_size,
                              hipStream_t stream) {
    // input order (interleaved theta/bias):
    // 0:W1 1:W2 2:b1 3:b2 4:theta_0 5:bias_0 6:theta_1 7:bias_1
    // 8:theta_2 9:bias_2 10:theta_3 11:bias_3
    const float* W1    = (const float*)d_in[0];
    const float* W2    = (const float*)d_in[1];
    const float* b1    = (const float*)d_in[2];
    const float* b2    = (const float*)d_in[3];
    const float* th0   = (const float*)d_in[4];
    const float* bias0 = (const float*)d_in[5];
    const float* th1   = (const float*)d_in[6];
    const float* bias1 = (const float*)d_in[7];
    const float* th2   = (const float*)d_in[8];
    const float* bias2 = (const float*)d_in[9];
    const float* th3   = (const float*)d_in[10];
    const float* bias3 = (const float*)d_in[11];

    float* out  = (float*)d_out;
    float* out0 = out;
    float* out1 = out + (size_t)NDIM * NDIM * CH;
    float* out2 = out1 + (size_t)NDIM * NDIM * CH;
    float* out3 = out2 + (size_t)NDIM * CH;

    float* ws = (float*)d_ws;

    // fused path needs: rowpart(524288) + colpart(524288) + rowsumF(32768) +
    // colsumF(32768) + sums(64) + R0..C1(65536) = 1,179,712 floats = 4,718,848 B
    const size_t FUSED_NEED = (size_t)1179712 * 4;

    if (ws_size >= FUSED_NEED) {
        float* rowpart = ws;                    // [2][16][1024][16]
        float* colpart = ws + 524288;           // [2][16][1024][16]
        float* rowsumF = ws + 1048576;          // [2][1024][16]
        float* colsumF = ws + 1081344;          // [2][1024][16]
        float* sums    = ws + 1114112;          // [4][16]
        float* R0      = ws + 1114176;
        float* C0      = R0 + 16384;
        float* R1      = C0 + 16384;
        float* C1      = R1 + 16384;

        k_fused<<<dim3(16, 16, 2), dim3(256), 0, stream>>>(W1, W2, rowpart, colpart);
        k_finalize<<<dim3(256), dim3(256), 0, stream>>>(rowpart, colpart, rowsumF, colsumF);
        k_sums<<<dim3(4), dim3(256), 0, stream>>>(rowsumF, b1, b2, sums);
        k_smalls2<<<dim3(64), dim3(256), 0, stream>>>(rowsumF, colsumF, sums, b1, b2,
                                                      th0, th1, th2, th3,
                                                      bias0, bias1, bias2, bias3,
                                                      R0, C0, R1, C1, out2, out3);
        k_main<<<dim3(4, NDIM, 2), dim3(256), 0, stream>>>(W1, W2, R0, C0, R1, C1,
                                                           th0, th1 + 2 * 256,
                                                           out0, out1);
    } else {
        // proven fallback (round-3 structure), 655,616 B workspace
        float* rowsum  = ws;                 // [2][1024][16]
        float* partial = ws + 32768;         // [2][2][1024][16]
        float* sums    = ws + 98304;         // [4][16]
        float* R0      = ws + 98368;
        float* C0      = R0 + 16384;
        float* R1      = C0 + 16384;
        float* C1      = R1 + 16384;

        k_rowsum<<<dim3(NDIM, 2), dim3(256), 0, stream>>>(W1, W2, rowsum);
        k_colsum_partial<<<dim3(128, 2, 2), dim3(256), 0, stream>>>(W1, W2, partial);
        k_sums<<<dim3(4), dim3(256), 0, stream>>>(rowsum, b1, b2, sums);
        k_smalls<<<dim3(64), dim3(256), 0, stream>>>(rowsum, partial, sums, b1, b2,
                                                     th0, th1, th2, th3,
                                                     bias0, bias1, bias2, bias3,
                                                     R0, C0, R1, C1, out2, out3);
        k_main<<<dim3(4, NDIM, 2), dim3(256), 0, stream>>>(W1, W2, R0, C0, R1, C1,
                                                           th0, th1 + 2 * 256,
                                                           out0, out1);
    }
}

// Round 5
// 104.121 us; speedup vs baseline: 1.0276x; 1.0276x over previous
//
#include <hip/hip_runtime.h>

#define NDIM 1024
#define CH 16
#define ROW_FLOATS (NDIM * CH)      // 16384 floats per row of W
#define ROW_F4 (ROW_FLOATS / 4)     // 4096 float4 per row

__device__ inline float4 f4add(float4 a, float4 b) {
    return make_float4(a.x + b.x, a.y + b.y, a.z + b.z, a.w + b.w);
}
__device__ inline float4 f4shfl_xor(float4 v, int m) {
    return make_float4(__shfl_xor(v.x, m), __shfl_xor(v.y, m),
                       __shfl_xor(v.z, m), __shfl_xor(v.w, m));
}

// ---------------------------------------------------------------------------
// k_fused: ONE pass over W producing BOTH chunked row partials and col
// partials (deterministic, no atomics). Partials land in the out0 region of
// d_out, which is dead scratch until k_main overwrites it at the end.
// Block = 64 cols x 64 rows tile. Thread t -> (j_local = t>>2, cq = t&3).
//   col partial: register accumulation over the 64 rows (thread-owned).
//   row partial: per-row shfl_xor reduce over the wave's 16 j's -> per-wave
//                LDS slice -> cross-wave reduce in epilogue.
// rowpart[z][chunk=bj][i][c], colpart[z][chunk=bi][j][c]   (16 chunks each)
// ---------------------------------------------------------------------------
__global__ __launch_bounds__(256) void k_fused(const float* __restrict__ W1,
                                               const float* __restrict__ W2,
                                               float* __restrict__ rowpart,
                                               float* __restrict__ colpart) {
    int t  = threadIdx.x;
    int bj = blockIdx.x, bi = blockIdx.y, z = blockIdx.z;
    int j0 = bj * 64, i0 = bi * 64;
    const float4* base = (const float4*)(z ? W2 : W1)
                       + (size_t)i0 * ROW_F4 + j0 * 4 + t;   // 4 float4 per j
    __shared__ float rowacc[4][64][16];   // [wave][row][ch] — 16 KB
    int w = t >> 6, lane = t & 63;
    float4 colacc = make_float4(0.f, 0.f, 0.f, 0.f);
#pragma unroll 4
    for (int k = 0; k < 64; ++k) {
        float4 v = base[(size_t)k * ROW_F4];
        colacc = f4add(colacc, v);
        float4 vr = v;                    // reduce over lane bits 2..5 (16 j's)
        vr = f4add(vr, f4shfl_xor(vr, 4));
        vr = f4add(vr, f4shfl_xor(vr, 8));
        vr = f4add(vr, f4shfl_xor(vr, 16));
        vr = f4add(vr, f4shfl_xor(vr, 32));
        if (lane < 4) {                   // lane == cq
            rowacc[w][k][lane * 4 + 0] = vr.x;
            rowacc[w][k][lane * 4 + 1] = vr.y;
            rowacc[w][k][lane * 4 + 2] = vr.z;
            rowacc[w][k][lane * 4 + 3] = vr.w;
        }
    }
    int jl = t >> 2, cq = t & 3;
    {   // column partial: thread owns (j0+jl, channels 4cq..4cq+3)
        size_t coff = (((size_t)z * 16 + bi) * NDIM + (j0 + jl)) * CH + cq * 4;
        *(float4*)(colpart + coff) = colacc;
    }
    __syncthreads();
    {   // row partial: thread -> (row r = t>>2, cq); reduce the 4 wave slices
        int r = t >> 2;
        const float4* ra = (const float4*)&rowacc[0][0][0];  // [(w*64+r)*4+cq]
        float4 s = f4add(f4add(ra[(0 * 64 + r) * 4 + cq], ra[(1 * 64 + r) * 4 + cq]),
                         f4add(ra[(2 * 64 + r) * 4 + cq], ra[(3 * 64 + r) * 4 + cq]));
        size_t roff = (((size_t)z * 16 + bj) * NDIM + (i0 + r)) * CH + cq * 4;
        *(float4*)(rowpart + roff) = s;
    }
}

// k_finalize: reduce the 16 chunks -> rowsumF[z][i][c], colsumF[z][j][c]
// (2 MB read, L2-resident)
__global__ __launch_bounds__(256) void k_finalize(const float* __restrict__ rowpart,
                                                  const float* __restrict__ colpart,
                                                  float* __restrict__ rowsumF,
                                                  float* __restrict__ colsumF) {
    int gt  = blockIdx.x * 256 + threadIdx.x;  // 0..65535
    int sel = gt >> 15;
    int rem = gt & 32767;                      // z*16384 + idx
    const float* src = sel ? colpart : rowpart;
    float* dst       = sel ? colsumF : rowsumF;
    int z = rem >> 14, idx = rem & 16383;
    const float* p = src + (size_t)z * 16 * 16384 + idx;
    float s = 0.f;
#pragma unroll
    for (int ch = 0; ch < 16; ++ch) s += p[ch * 16384];
    dst[rem] = s;
}

// ---------------------------------------------------------------------------
// k_sums: block 0: sumW1 (from rowsumF z0), 1: sumW2, 2: sum b1, 3: sum b2
// ---------------------------------------------------------------------------
__global__ __launch_bounds__(256) void k_sums(const float* __restrict__ rowsum,
                                              const float* __restrict__ b1,
                                              const float* __restrict__ b2,
                                              float* __restrict__ sums) {
    int tgt = blockIdx.x;
    const float* src = (tgt == 0) ? rowsum
                     : (tgt == 1) ? rowsum + 16384
                     : (tgt == 2) ? b1 : b2;
    int t = threadIdx.x;
    const float4* s4 = (const float4*)src;
    float4 a = make_float4(0.f, 0.f, 0.f, 0.f);
#pragma unroll
    for (int k = 0; k < 16; ++k) a = f4add(a, s4[t + 256 * k]);
    __shared__ float4 lds[256];
    lds[t] = a;
    __syncthreads();
    if (t < 64) {
        float4 s = lds[t];
#pragma unroll
        for (int o = 1; o < 4; ++o) s = f4add(s, lds[t + 64 * o]);
        lds[t] = s;
    }
    __syncthreads();
    if (t < 4) {
        float4 s = make_float4(0.f, 0.f, 0.f, 0.f);
#pragma unroll
        for (int m = 0; m < 16; ++m) s = f4add(s, lds[t + 4 * m]);
        float* dst = sums + tgt * 16 + 4 * t;
        dst[0] = s.x; dst[1] = s.y; dst[2] = s.z; dst[3] = s.w;
    }
}

// ---------------------------------------------------------------------------
// k_smalls: all O(N) outputs. Thread -> (i, o).
//   R0[i][o] = rsW1[i]·θ0_1
//   C0[j][o] = csW1[j]·θ0_2 + rsW2[j]·θ0_4 + b1[j]·θ0_6 + const0 + bias0
//   R1[i][o] = csW1[i]·θ1_0 + rsW2[i]·θ1_3 + b1[i]·θ1_6
//   C1[j][o] = csW2[j]·θ1_4 + b2[j]·θ1_8 + const1 + bias1
//   out2/out3 with constants folded. theta [k][c][o] at k*256 + c*16 + o
// ---------------------------------------------------------------------------
__global__ __launch_bounds__(256) void k_smalls(const float* __restrict__ rowsum,
                                                const float* __restrict__ colsum,
                                                const float* __restrict__ sums,
                                                const float* __restrict__ b1,
                                                const float* __restrict__ b2,
                                                const float* __restrict__ th0,
                                                const float* __restrict__ th1,
                                                const float* __restrict__ th2,
                                                const float* __restrict__ th3,
                                                const float* __restrict__ bias0,
                                                const float* __restrict__ bias1,
                                                const float* __restrict__ bias2,
                                                const float* __restrict__ bias3,
                                                float* __restrict__ R0, float* __restrict__ C0,
                                                float* __restrict__ R1, float* __restrict__ C1,
                                                float* __restrict__ out2, float* __restrict__ out3) {
    int gt = blockIdx.x * 256 + threadIdx.x;
    int i = gt >> 4, o = gt & 15;
    const float* rs1 = rowsum + i * 16;
    const float* rs2 = rowsum + 16384 + i * 16;
    const float* cs1 = colsum + i * 16;
    const float* cs2 = colsum + 16384 + i * 16;
    const float* b1i = b1 + i * 16;
    const float* b2i = b2 + i * 16;
    float r0 = 0.f, c0a = 0.f, r1 = 0.f, c1a = 0.f, o2 = 0.f, o3 = 0.f;
    float k0 = 0.f, k1 = 0.f, k2 = 0.f, k3 = 0.f;
#pragma unroll
    for (int c = 0; c < 16; ++c) {
        float sW1 = sums[c], sW2 = sums[16 + c], sb1 = sums[32 + c], sb2 = sums[48 + c];
        r0  += rs1[c] * th0[(1 * 16 + c) * 16 + o];
        c0a += cs1[c] * th0[(2 * 16 + c) * 16 + o]
             + rs2[c] * th0[(4 * 16 + c) * 16 + o]
             + b1i[c] * th0[(6 * 16 + c) * 16 + o];
        k0  += sW1 * th0[(3 * 16 + c) * 16 + o] + sW2 * th0[(5 * 16 + c) * 16 + o]
             + sb1 * th0[(7 * 16 + c) * 16 + o] + sb2 * th0[(8 * 16 + c) * 16 + o];
        r1  += cs1[c] * th1[(0 * 16 + c) * 16 + o]
             + rs2[c] * th1[(3 * 16 + c) * 16 + o]
             + b1i[c] * th1[(6 * 16 + c) * 16 + o];
        c1a += cs2[c] * th1[(4 * 16 + c) * 16 + o]
             + b2i[c] * th1[(8 * 16 + c) * 16 + o];
        k1  += sW1 * th1[(1 * 16 + c) * 16 + o] + sW2 * th1[(5 * 16 + c) * 16 + o]
             + sb1 * th1[(7 * 16 + c) * 16 + o] + sb2 * th1[(9 * 16 + c) * 16 + o];
        o2  += cs1[c] * th2[(0 * 16 + c) * 16 + o]
             + rs2[c] * th2[(2 * 16 + c) * 16 + o]
             + b1i[c] * th2[(4 * 16 + c) * 16 + o];
        k2  += sW1 * th2[(1 * 16 + c) * 16 + o] + sW2 * th2[(3 * 16 + c) * 16 + o]
             + sb1 * th2[(5 * 16 + c) * 16 + o] + sb2 * th2[(6 * 16 + c) * 16 + o];
        o3  += cs2[c] * th3[(1 * 16 + c) * 16 + o]
             + b2i[c] * th3[(4 * 16 + c) * 16 + o];
        k3  += sW1 * th3[(0 * 16 + c) * 16 + o] + sW2 * th3[(2 * 16 + c) * 16 + o]
             + sb1 * th3[(3 * 16 + c) * 16 + o] + sb2 * th3[(5 * 16 + c) * 16 + o];
    }
    R0[gt]   = r0;
    C0[gt]   = c0a + k0 + bias0[o];
    R1[gt]   = r1;
    C1[gt]   = c1a + k1 + bias1[o];
    out2[gt] = o2 + k2 + bias2[o];
    out3[gt] = o3 + k3 + bias3[o];
}

// ---------------------------------------------------------------------------
// k_main: streaming pass (overwrites out0 — including the partial scratch).
//   out0[i,j,:] = W1[i,j,:]·θ0_0 + R0[i] + C0[j]
//   out1[i,j,:] = W2[i,j,:]·θ1_2 + R1[i] + C1[j]
// ---------------------------------------------------------------------------
__global__ __launch_bounds__(256) void k_main(const float* __restrict__ W1,
                                              const float* __restrict__ W2,
                                              const float* __restrict__ R0,
                                              const float* __restrict__ C0,
                                              const float* __restrict__ R1,
                                              const float* __restrict__ C1,
                                              const float* __restrict__ th0,
                                              const float* __restrict__ th1,
                                              float* __restrict__ out0,
                                              float* __restrict__ out1) {
    int z = blockIdx.z;
    const float* W  = z ? W2 : W1;
    const float* R  = z ? R1 : R0;
    const float* Cc = z ? C1 : C0;
    const float* TH = z ? th1 : th0;
    float* out      = z ? out1 : out0;

    int t = threadIdx.x;
    int i = blockIdx.y;
    int j = blockIdx.x * 256 + t;

    __shared__ float th[256];
    __shared__ float r[16];
    th[t] = TH[t];
    if (t < 16) r[t] = R[i * 16 + t];
    __syncthreads();

    size_t base = ((size_t)i * NDIM + j) * CH;
    const float4* xp = (const float4*)(W + base);
    float4 x0 = xp[0], x1 = xp[1], x2 = xp[2], x3 = xp[3];
    float x[16] = {x0.x, x0.y, x0.z, x0.w, x1.x, x1.y, x1.z, x1.w,
                   x2.x, x2.y, x2.z, x2.w, x3.x, x3.y, x3.z, x3.w};

    const float4* cj = (const float4*)(Cc + j * 16);
    float4 c0 = cj[0], c1 = cj[1], c2 = cj[2], c3 = cj[3];
    float acc[16] = {c0.x, c0.y, c0.z, c0.w, c1.x, c1.y, c1.z, c1.w,
                     c2.x, c2.y, c2.z, c2.w, c3.x, c3.y, c3.z, c3.w};
#pragma unroll
    for (int o = 0; o < 16; ++o) acc[o] += r[o];
#pragma unroll
    for (int c = 0; c < 16; ++c) {
        float xv = x[c];
#pragma unroll
        for (int o = 0; o < 16; ++o) acc[o] += xv * th[c * 16 + o];
    }
    float4* op = (float4*)(out + base);
    op[0] = make_float4(acc[0],  acc[1],  acc[2],  acc[3]);
    op[1] = make_float4(acc[4],  acc[5],  acc[6],  acc[7]);
    op[2] = make_float4(acc[8],  acc[9],  acc[10], acc[11]);
    op[3] = make_float4(acc[12], acc[13], acc[14], acc[15]);
}

extern "C" void kernel_launch(void* const* d_in, const int* in_sizes, int n_in,
                              void* d_out, int out_size, void* d_ws, size_t ws_size,
                              hipStream_t stream) {
    // input order (interleaved theta/bias):
    // 0:W1 1:W2 2:b1 3:b2 4:theta_0 5:bias_0 6:theta_1 7:bias_1
    // 8:theta_2 9:bias_2 10:theta_3 11:bias_3
    const float* W1    = (const float*)d_in[0];
    const float* W2    = (const float*)d_in[1];
    const float* b1    = (const float*)d_in[2];
    const float* b2    = (const float*)d_in[3];
    const float* th0   = (const float*)d_in[4];
    const float* bias0 = (const float*)d_in[5];
    const float* th1   = (const float*)d_in[6];
    const float* bias1 = (const float*)d_in[7];
    const float* th2   = (const float*)d_in[8];
    const float* bias2 = (const float*)d_in[9];
    const float* th3   = (const float*)d_in[10];
    const float* bias3 = (const float*)d_in[11];

    float* out  = (float*)d_out;
    float* out0 = out;
    float* out1 = out + (size_t)NDIM * NDIM * CH;
    float* out2 = out1 + (size_t)NDIM * NDIM * CH;
    float* out3 = out2 + (size_t)NDIM * CH;

    // chunk partials live in the (not-yet-written) out0 region: 4 MB of the
    // 64 MB out0 tensor, fully overwritten by k_main afterwards.
    float* rowpart = out0;                  // [2][16][1024][16] = 524288
    float* colpart = out0 + 524288;         // [2][16][1024][16] = 524288

    // workspace: 131,136 floats = 524,544 B (≤ proven 655,616 B budget)
    float* ws      = (float*)d_ws;
    float* rowsumF = ws;                    // [2][1024][16] = 32768
    float* colsumF = ws + 32768;            // [2][1024][16] = 32768
    float* sums    = ws + 65536;            // [4][16] = 64
    float* R0      = ws + 65600;            // 16384 each
    float* C0      = R0 + 16384;
    float* R1      = C0 + 16384;
    float* C1      = R1 + 16384;

    k_fused<<<dim3(16, 16, 2), dim3(256), 0, stream>>>(W1, W2, rowpart, colpart);
    k_finalize<<<dim3(256), dim3(256), 0, stream>>>(rowpart, colpart, rowsumF, colsumF);
    k_sums<<<dim3(4), dim3(256), 0, stream>>>(rowsumF, b1, b2, sums);
    k_smalls<<<dim3(64), dim3(256), 0, stream>>>(rowsumF, colsumF, sums, b1, b2,
                                                 th0, th1, th2, th3,
                                                 bias0, bias1, bias2, bias3,
                                                 R0, C0, R1, C1, out2, out3);
    k_main<<<dim3(4, NDIM, 2), dim3(256), 0, stream>>>(W1, W2, R0, C0, R1, C1,
                                                       th0, th1 + 2 * 256,
                                                       out0, out1);
}